// Round 1
// baseline (1317.861 us; speedup 1.0000x reference)
//
#include <hip/hip_runtime.h>
#include <hip/hip_bf16.h>
#include <math.h>

#define EPSV 1e-5f

// problem sizes (fixed by setup_inputs)
#define B_    16
#define CIN   64
#define H_IN  256
#define W_IN  256
#define COUT  64
#define H_OUT 254
#define W_OUT 254

// conv tiling
#define TW 64
#define TH 4
#define NWT 4          // ceil(254/64)
#define NHT 64         // ceil(254/4)
#define NBLK (B_ * NWT * NHT)   // 4096

// ---------------------------------------------------------------------------
// Build M = A*S1*A*S0 from q_params (L=2, Q=4, 3)
// ---------------------------------------------------------------------------
__device__ __forceinline__ void compute_M(const float* __restrict__ qp, float M[4][4]) {
    float s[2][4];
#pragma unroll
    for (int l = 0; l < 2; ++l)
#pragma unroll
        for (int q = 0; q < 4; ++q) {
            float tx = qp[l * 12 + q * 3 + 0];
            float ty = qp[l * 12 + q * 3 + 1];
            float tz = qp[l * 12 + q * 3 + 2];
            s[l][q] = cosf((tx + ty) * 0.5f) * cosf(tz);
        }
    // T[i][j] = s1[i] * A[i][j] * s0[j];  M = A * T
    float T[4][4];
#pragma unroll
    for (int i = 0; i < 4; ++i)
#pragma unroll
        for (int j = 0; j < 4; ++j) {
            float Aij = ((i >> 1) == (j >> 1)) ? 0.5f : 0.0f;
            T[i][j] = s[1][i] * Aij * s[0][j];
        }
#pragma unroll
    for (int i = 0; i < 4; ++i)
#pragma unroll
        for (int j = 0; j < 4; ++j) {
            int k0 = (i >> 1) * 2;
            M[i][j] = 0.5f * (T[k0][j] + T[k0 + 1][j]);
        }
}

// ---------------------------------------------------------------------------
// Kernel 1: w_eff[ci][k][co] = sum_{q,q'} w_post[co,q] M[q,q'] w_pre[q',ci,k]
// layout [ci][k][co] so the conv kernel can bulk-copy contiguous chunks.
// ---------------------------------------------------------------------------
__global__ void prep_weff(const float* __restrict__ w_pre,
                          const float* __restrict__ q_params,
                          const float* __restrict__ w_post,
                          float* __restrict__ weff) {
    int idx = blockIdx.x * 256 + threadIdx.x;
    if (idx >= CIN * 9 * COUT) return;
    float M[4][4];
    compute_M(q_params, M);
    int co = idx & 63;
    int k  = (idx >> 6) % 9;
    int ci = idx / (64 * 9);
    float v[4];
#pragma unroll
    for (int q = 0; q < 4; ++q) v[q] = w_pre[q * (CIN * 9) + ci * 9 + k];
    float mv[4];
#pragma unroll
    for (int q = 0; q < 4; ++q)
        mv[q] = M[q][0] * v[0] + M[q][1] * v[1] + M[q][2] * v[2] + M[q][3] * v[3];
    float val = 0.f;
#pragma unroll
    for (int q = 0; q < 4; ++q) val += w_post[co * 4 + q] * mv[q];
    weff[(ci * 9 + k) * 64 + co] = val;
}

// ---------------------------------------------------------------------------
// Kernel 2: direct 3x3 conv, 64 cout, tile 64W x 4H, per-thread 8co x 8w.
// Also emits per-block per-channel sum / sumsq partials for BN.
// ---------------------------------------------------------------------------
__global__ __launch_bounds__(256) void conv_main(
    const float* __restrict__ x, const float* __restrict__ weff,
    float* __restrict__ out, float* __restrict__ psum, float* __restrict__ psq)
{
    __shared__ float smem[3264 + 4608];
    float (*xs)[6][68]  = (float (*)[6][68])smem;           // [ci][row][col]
    float (*wsh)[9][64] = (float (*)[9][64])(smem + 3264);  // [ci][k][co]

    const int tid = threadIdx.x;
    const int bid = blockIdx.x;
    const int b   = bid >> 8;
    const int wt  = (bid >> 6) & 3;
    const int ht  = bid & 63;
    const int hb  = ht * TH;
    const int wb  = wt * TW;

    const int w_t  = tid & 7;          // 8 w-groups of 8 cols
    const int h_t  = (tid >> 3) & 3;   // 4 rows
    const int co_t = tid >> 5;         // 8 co-groups of 8 couts
    const int w0   = w_t * 8;
    const int co0  = co_t * 8;

    float acc[8][8];
#pragma unroll
    for (int c = 0; c < 8; ++c)
#pragma unroll
        for (int w = 0; w < 8; ++w) acc[c][w] = 0.f;

    for (int cib = 0; cib < CIN; cib += 8) {
        // ---- stage x tile: 8ci x 6rows x 68cols (cols 66..67 zero pad)
        for (int i = tid; i < 3264; i += 256) {
            int c  = i % 68;
            int t2 = i / 68;
            int r  = t2 % 6;
            int ci = t2 / 6;
            int gh = hb + r;
            int gw = wb + c;
            float v = 0.f;
            if (c < 66 && gh < H_IN && gw < W_IN)
                v = x[(((size_t)(b * CIN + cib + ci)) * H_IN + gh) * W_IN + gw];
            xs[ci][r][c] = v;
        }
        // ---- stage weights: contiguous 8*9*64 floats
        {
            const float4* wsrc = (const float4*)(weff + (size_t)cib * 576);
            float4* wdst = (float4*)wsh;
            for (int i = tid; i < 1152; i += 256) wdst[i] = wsrc[i];
        }
        __syncthreads();

#pragma unroll 2
        for (int ci = 0; ci < 8; ++ci) {
#pragma unroll
            for (int kh = 0; kh < 3; ++kh) {
                float rx[12];
                const float4* xp = (const float4*)&xs[ci][h_t + kh][w0];
                float4 x0 = xp[0], x1 = xp[1], x2 = xp[2];
                rx[0] = x0.x; rx[1] = x0.y; rx[2]  = x0.z; rx[3]  = x0.w;
                rx[4] = x1.x; rx[5] = x1.y; rx[6]  = x1.z; rx[7]  = x1.w;
                rx[8] = x2.x; rx[9] = x2.y; rx[10] = x2.z; rx[11] = x2.w;
#pragma unroll
                for (int kw = 0; kw < 3; ++kw) {
                    const float4* wp = (const float4*)&wsh[ci][kh * 3 + kw][co0];
                    float4 wa = wp[0], wb4 = wp[1];
                    float wv[8] = {wa.x, wa.y, wa.z, wa.w, wb4.x, wb4.y, wb4.z, wb4.w};
#pragma unroll
                    for (int c = 0; c < 8; ++c)
#pragma unroll
                        for (int w = 0; w < 8; ++w)
                            acc[c][w] = fmaf(wv[c], rx[w + kw], acc[c][w]);
                }
            }
        }
        __syncthreads();
    }

    // ---- store conv output (pre-BN) to d_out
    const int gh = hb + h_t;
    const bool hvalid = (gh < H_OUT);
    if (hvalid) {
#pragma unroll
        for (int c = 0; c < 8; ++c) {
            const int co = co0 + c;
            float* op = out + (((size_t)(b * COUT + co)) * H_OUT + gh) * W_OUT + wb + w0;
#pragma unroll
            for (int w = 0; w < 8; ++w)
                if (wb + w0 + w < W_OUT) op[w] = acc[c][w];
        }
    }

    // ---- per-thread BN partials over valid outputs
    float ls[8], lq[8];
#pragma unroll
    for (int c = 0; c < 8; ++c) { ls[c] = 0.f; lq[c] = 0.f; }
    if (hvalid) {
#pragma unroll
        for (int c = 0; c < 8; ++c)
#pragma unroll
            for (int w = 0; w < 8; ++w)
                if (wb + w0 + w < W_OUT) {
                    float v = acc[c][w];
                    ls[c] += v;
                    lq[c] += v * v;
                }
    }
    __syncthreads();   // smem compute reads done; reuse as reduction space
    float* rs = smem;          // [64][32]
    float* rq = smem + 2048;   // [64][32]
    const int slot = h_t * 8 + w_t;
#pragma unroll
    for (int c = 0; c < 8; ++c) {
        rs[(co0 + c) * 32 + slot] = ls[c];
        rq[(co0 + c) * 32 + slot] = lq[c];
    }
    __syncthreads();
    if (tid < 64) {
        float s = 0.f, q = 0.f;
#pragma unroll
        for (int j = 0; j < 32; ++j) { s += rs[tid * 32 + j]; q += rq[tid * 32 + j]; }
        psum[(size_t)tid * NBLK + bid] = s;
        psq [(size_t)tid * NBLK + bid] = q;
    }
}

// ---------------------------------------------------------------------------
// Kernel 3: reduce partials -> per-channel BN scale a, shift c
// ---------------------------------------------------------------------------
__global__ void reduce_scales(const float* __restrict__ psum,
                              const float* __restrict__ psq,
                              const float* __restrict__ gamma,
                              const float* __restrict__ beta,
                              float* __restrict__ scales) {
    const int co  = blockIdx.x;
    const int tid = threadIdx.x;
    float s = 0.f, q = 0.f;
    for (int i = tid; i < NBLK; i += 256) {
        s += psum[(size_t)co * NBLK + i];
        q += psq [(size_t)co * NBLK + i];
    }
    __shared__ float sh[4], sh2[4];
#pragma unroll
    for (int off = 32; off; off >>= 1) {
        s += __shfl_down(s, off);
        q += __shfl_down(q, off);
    }
    if ((tid & 63) == 0) { sh[tid >> 6] = s; sh2[tid >> 6] = q; }
    __syncthreads();
    if (tid == 0) {
        float S  = sh[0] + sh[1] + sh[2] + sh[3];
        float Q2 = sh2[0] + sh2[1] + sh2[2] + sh2[3];
        const float N = (float)(B_ * H_OUT * W_OUT);
        float mean = S / N;
        float var  = Q2 / N - mean * mean;
        float a = gamma[co] * rsqrtf(var + EPSV);
        float c = beta[co] - mean * a;
        scales[co]      = a;
        scales[64 + co] = c;
    }
}

// ---------------------------------------------------------------------------
// Kernel 4: in-place BN + ReLU over d_out (float4 vectorized; HW*4 aligned)
// ---------------------------------------------------------------------------
__global__ __launch_bounds__(256) void bn_relu(float* __restrict__ out,
                                               const float* __restrict__ scales) {
    __shared__ float sa[64], sc[64];
    if (threadIdx.x < 64) sa[threadIdx.x] = scales[threadIdx.x];
    else if (threadIdx.x < 128) sc[threadIdx.x - 64] = scales[threadIdx.x];
    __syncthreads();
    const unsigned total4 = (unsigned)(B_ * COUT * H_OUT * W_OUT / 4);  // 16,516,096
    const unsigned plane4 = (unsigned)(H_OUT * W_OUT / 4);              // 16,129
    float4* p = (float4*)out;
    for (unsigned i = blockIdx.x * 256u + threadIdx.x; i < total4; i += gridDim.x * 256u) {
        unsigned co = (i / plane4) & 63u;
        float a = sa[co], c = sc[co];
        float4 v = p[i];
        v.x = fmaxf(fmaf(v.x, a, c), 0.f);
        v.y = fmaxf(fmaf(v.y, a, c), 0.f);
        v.z = fmaxf(fmaf(v.z, a, c), 0.f);
        v.w = fmaxf(fmaf(v.w, a, c), 0.f);
        p[i] = v;
    }
}

// ---------------------------------------------------------------------------
extern "C" void kernel_launch(void* const* d_in, const int* in_sizes, int n_in,
                              void* d_out, int out_size, void* d_ws, size_t ws_size,
                              hipStream_t stream) {
    const float* x        = (const float*)d_in[0];
    const float* w_pre    = (const float*)d_in[1];
    const float* q_params = (const float*)d_in[2];
    const float* w_post   = (const float*)d_in[3];
    // d_in[4] = b_post: cancels inside batchnorm, unused
    const float* gamma    = (const float*)d_in[5];
    const float* beta     = (const float*)d_in[6];
    float* out = (float*)d_out;

    float* ws     = (float*)d_ws;
    float* weff   = ws;                        // 36,864 floats
    float* psum   = weff + CIN * 9 * COUT;     // 64 * 4096
    float* psq    = psum + (size_t)COUT * NBLK;
    float* scales = psq  + (size_t)COUT * NBLK; // 128 floats

    prep_weff<<<(CIN * 9 * COUT + 255) / 256, 256, 0, stream>>>(w_pre, q_params, w_post, weff);
    conv_main<<<NBLK, 256, 0, stream>>>(x, weff, out, psum, psq);
    reduce_scales<<<COUT, 256, 0, stream>>>(psum, psq, gamma, beta, scales);
    bn_relu<<<4096, 256, 0, stream>>>(out, scales);
}

// Round 2
// 1214.216 us; speedup vs baseline: 1.0854x; 1.0854x over previous
//
#include <hip/hip_runtime.h>
#include <hip/hip_bf16.h>
#include <math.h>

typedef __attribute__((ext_vector_type(8))) short short8;
typedef __attribute__((ext_vector_type(4))) float floatx4;

#define EPSV 1e-5f

#define B_    16
#define CIN   64
#define H_IN  256
#define W_IN  256
#define COUT  64
#define H_OUT 254
#define W_OUT 254

#define NWT 4
#define NHT 64
#define NBLK (B_ * NWT * NHT)   // 4096

// ci padded stride inside LDS x-tile (72*2B = 144B: keeps 16B alignment,
// makes col-stride 9 x 16B units -> <=2-way bank aliasing per quarter wave)
#define CIP 72

__device__ __forceinline__ unsigned short bf16u(float v) {
    __hip_bfloat16 b = __float2bfloat16(v);
    return *reinterpret_cast<unsigned short*>(&b);
}

// ---------------------------------------------------------------------------
// M = A*S1*A*S0 from q_params (L=2, Q=4, 3)
// ---------------------------------------------------------------------------
__device__ __forceinline__ void compute_M(const float* __restrict__ qp, float M[4][4]) {
    float s[2][4];
#pragma unroll
    for (int l = 0; l < 2; ++l)
#pragma unroll
        for (int q = 0; q < 4; ++q) {
            float tx = qp[l * 12 + q * 3 + 0];
            float ty = qp[l * 12 + q * 3 + 1];
            float tz = qp[l * 12 + q * 3 + 2];
            s[l][q] = cosf((tx + ty) * 0.5f) * cosf(tz);
        }
    float T[4][4];
#pragma unroll
    for (int i = 0; i < 4; ++i)
#pragma unroll
        for (int j = 0; j < 4; ++j) {
            float Aij = ((i >> 1) == (j >> 1)) ? 0.5f : 0.0f;
            T[i][j] = s[1][i] * Aij * s[0][j];
        }
#pragma unroll
    for (int i = 0; i < 4; ++i)
#pragma unroll
        for (int j = 0; j < 4; ++j) {
            int k0 = (i >> 1) * 2;
            M[i][j] = 0.5f * (T[k0][j] + T[k0 + 1][j]);
        }
}

// ---------------------------------------------------------------------------
// Kernel 1: fold w_pre/M/w_post -> bf16 weff[t][co][ci]   (t = kh*3+kw)
// ---------------------------------------------------------------------------
__global__ void prep_weff(const float* __restrict__ w_pre,
                          const float* __restrict__ q_params,
                          const float* __restrict__ w_post,
                          unsigned short* __restrict__ weffb) {
    int idx = blockIdx.x * 256 + threadIdx.x;
    if (idx >= 9 * 64 * 64) return;
    float M[4][4];
    compute_M(q_params, M);
    int ci = idx & 63;
    int co = (idx >> 6) & 63;
    int t  = idx >> 12;
    float v[4];
#pragma unroll
    for (int q = 0; q < 4; ++q) v[q] = w_pre[q * 576 + ci * 9 + t];
    float mv[4];
#pragma unroll
    for (int q = 0; q < 4; ++q)
        mv[q] = M[q][0] * v[0] + M[q][1] * v[1] + M[q][2] * v[2] + M[q][3] * v[3];
    float val = 0.f;
#pragma unroll
    for (int q = 0; q < 4; ++q) val += w_post[co * 4 + q] * mv[q];
    weffb[idx] = bf16u(val);
}

// ---------------------------------------------------------------------------
// Kernel 2: MFMA implicit-GEMM conv. Block: 64co x (4 rows x 64 cols).
// 9 taps x (K=64) GEMM, A = weights (global, dbuf), B = LDS x-tile.
// ---------------------------------------------------------------------------
#define LOADA(dst, t_)                                                          \
    do {                                                                        \
        const unsigned short* wp_ = weffb + (t_) * 4096 + l15 * 64 + 8 * l4;    \
        _Pragma("unroll") for (int mi = 0; mi < 4; ++mi)                        \
        _Pragma("unroll") for (int ks = 0; ks < 2; ++ks)                        \
            dst[mi][ks] = *reinterpret_cast<const short8*>(wp_ + mi * 1024 + ks * 32); \
    } while (0)

__global__ __launch_bounds__(256, 2) void conv_mfma(
    const float* __restrict__ x, const unsigned short* __restrict__ weffb,
    float* __restrict__ out, float* __restrict__ psum, float* __restrict__ psq)
{
    __shared__ __align__(16) unsigned short xs[6 * 66 * CIP];  // 57,024 B
    __shared__ float ssum[4][64];
    __shared__ float ssq[4][64];

    const int tid  = threadIdx.x;
    const int bid  = blockIdx.x;
    const int b    = bid >> 8;
    const int wt   = (bid >> 6) & 3;
    const int ht   = bid & 63;
    const int hb   = ht * 4;
    const int wb   = wt * 64;
    const int wave = tid >> 6;
    const int lane = tid & 63;
    const int l15  = lane & 15;
    const int l4   = lane >> 4;

    // ---- stage x tile (once): [row 0..5][col 0..65][ci] as bf16
    for (int seg = wave; seg < 384; seg += 4) {          // seg = ci*6 + r
        int ci = seg / 6;
        int r  = seg - ci * 6;
        int gh = hb + r;
        const float* xrow = x + (((size_t)(b * 64 + ci)) * 256 + gh) * 256 + wb;
        float v = 0.f;
        if (gh < 256 && wb + lane < 256) v = xrow[lane];
        xs[(r * 66 + lane) * CIP + ci] = bf16u(v);
        if (lane < 2) {
            int c2 = 64 + lane;
            float v2 = 0.f;
            if (gh < 256 && wb + c2 < 256) v2 = xrow[c2];
            xs[(r * 66 + c2) * CIP + ci] = bf16u(v2);
        }
    }
    __syncthreads();

    floatx4 acc[4][4];
#pragma unroll
    for (int mi = 0; mi < 4; ++mi)
#pragma unroll
        for (int nf = 0; nf < 4; ++nf) acc[mi][nf] = 0.f;

    short8 afA[4][2], afB[4][2];
    LOADA(afA, 0);

#pragma unroll
    for (int kh = 0; kh < 3; ++kh) {
#pragma unroll
        for (int kw = 0; kw < 3; ++kw) {
            const int t = kh * 3 + kw;
            // prefetch next tap's A fragments into the other buffer
            if (t < 8) {
                if (t & 1) { LOADA(afA, t + 1); }
                else       { LOADA(afB, t + 1); }
            }
            // B fragments from LDS
            short8 bf[4][2];
            const unsigned short* xb = xs + ((wave + kh) * 66 + kw + l15) * CIP + 8 * l4;
#pragma unroll
            for (int nf = 0; nf < 4; ++nf)
#pragma unroll
                for (int ks = 0; ks < 2; ++ks)
                    bf[nf][ks] = *reinterpret_cast<const short8*>(xb + nf * 16 * CIP + ks * 32);
#pragma unroll
            for (int mi = 0; mi < 4; ++mi)
#pragma unroll
                for (int nf = 0; nf < 4; ++nf)
#pragma unroll
                    for (int ks = 0; ks < 2; ++ks) {
                        const short8& a = (t & 1) ? afB[mi][ks] : afA[mi][ks];
                        acc[mi][nf] = __builtin_amdgcn_mfma_f32_16x16x32_bf16(
                            a, bf[nf][ks], acc[mi][nf], 0, 0, 0);
                    }
        }
    }

    // ---- store conv output + BN partials
    const int  gh_o   = hb + wave;
    const bool hvalid = gh_o < H_OUT;
    float ps[4][4], pq[4][4];   // [mi][r]
#pragma unroll
    for (int mi = 0; mi < 4; ++mi)
#pragma unroll
        for (int r = 0; r < 4; ++r) { ps[mi][r] = 0.f; pq[mi][r] = 0.f; }

#pragma unroll
    for (int mi = 0; mi < 4; ++mi)
#pragma unroll
        for (int nf = 0; nf < 4; ++nf) {
            const int  gw_o = wb + 16 * nf + l15;
            const bool vpix = hvalid && (gw_o < W_OUT);
#pragma unroll
            for (int r = 0; r < 4; ++r) {
                float val = acc[mi][nf][r];
                if (vpix) {
                    const int co = 16 * mi + 4 * l4 + r;
                    out[(((size_t)(b * 64 + co)) * H_OUT + gh_o) * W_OUT + gw_o] = val;
                    ps[mi][r] += val;
                    pq[mi][r] += val * val;
                }
            }
        }

    // reduce over the 16 fragment columns (same channel set per quarter-wave)
#pragma unroll
    for (int mi = 0; mi < 4; ++mi)
#pragma unroll
        for (int r = 0; r < 4; ++r) {
            float s = ps[mi][r], q = pq[mi][r];
#pragma unroll
            for (int off = 1; off < 16; off <<= 1) {
                s += __shfl_xor(s, off);
                q += __shfl_xor(q, off);
            }
            if (l15 == 0) {
                ssum[wave][16 * mi + 4 * l4 + r] = s;
                ssq [wave][16 * mi + 4 * l4 + r] = q;
            }
        }
    __syncthreads();
    if (tid < 64) {
        float s = ssum[0][tid] + ssum[1][tid] + ssum[2][tid] + ssum[3][tid];
        float q = ssq [0][tid] + ssq [1][tid] + ssq [2][tid] + ssq [3][tid];
        psum[(size_t)tid * NBLK + bid] = s;
        psq [(size_t)tid * NBLK + bid] = q;
    }
}

// ---------------------------------------------------------------------------
// Kernel 3: reduce partials -> per-channel BN scale a, shift c
// ---------------------------------------------------------------------------
__global__ void reduce_scales(const float* __restrict__ psum,
                              const float* __restrict__ psq,
                              const float* __restrict__ gamma,
                              const float* __restrict__ beta,
                              float* __restrict__ scales) {
    const int co  = blockIdx.x;
    const int tid = threadIdx.x;
    float s = 0.f, q = 0.f;
    for (int i = tid; i < NBLK; i += 256) {
        s += psum[(size_t)co * NBLK + i];
        q += psq [(size_t)co * NBLK + i];
    }
    __shared__ float sh[4], sh2[4];
#pragma unroll
    for (int off = 32; off; off >>= 1) {
        s += __shfl_down(s, off);
        q += __shfl_down(q, off);
    }
    if ((tid & 63) == 0) { sh[tid >> 6] = s; sh2[tid >> 6] = q; }
    __syncthreads();
    if (tid == 0) {
        float S  = sh[0] + sh[1] + sh[2] + sh[3];
        float Q2 = sh2[0] + sh2[1] + sh2[2] + sh2[3];
        const float N = (float)(B_ * H_OUT * W_OUT);
        float mean = S / N;
        float var  = Q2 / N - mean * mean;
        float a = gamma[co] * rsqrtf(var + EPSV);
        float c = beta[co] - mean * a;
        scales[co]      = a;
        scales[64 + co] = c;
    }
}

// ---------------------------------------------------------------------------
// Kernel 4: in-place BN + ReLU over d_out (float4 vectorized)
// ---------------------------------------------------------------------------
__global__ __launch_bounds__(256) void bn_relu(float* __restrict__ out,
                                               const float* __restrict__ scales) {
    __shared__ float sa[64], sc[64];
    if (threadIdx.x < 64) sa[threadIdx.x] = scales[threadIdx.x];
    else if (threadIdx.x < 128) sc[threadIdx.x - 64] = scales[threadIdx.x];
    __syncthreads();
    const unsigned total4 = (unsigned)(B_ * COUT * H_OUT * W_OUT / 4);
    const unsigned plane4 = (unsigned)(H_OUT * W_OUT / 4);
    float4* p = (float4*)out;
    for (unsigned i = blockIdx.x * 256u + threadIdx.x; i < total4; i += gridDim.x * 256u) {
        unsigned co = (i / plane4) & 63u;
        float a = sa[co], c = sc[co];
        float4 v = p[i];
        v.x = fmaxf(fmaf(v.x, a, c), 0.f);
        v.y = fmaxf(fmaf(v.y, a, c), 0.f);
        v.z = fmaxf(fmaf(v.z, a, c), 0.f);
        v.w = fmaxf(fmaf(v.w, a, c), 0.f);
        p[i] = v;
    }
}

// ---------------------------------------------------------------------------
extern "C" void kernel_launch(void* const* d_in, const int* in_sizes, int n_in,
                              void* d_out, int out_size, void* d_ws, size_t ws_size,
                              hipStream_t stream) {
    const float* x        = (const float*)d_in[0];
    const float* w_pre    = (const float*)d_in[1];
    const float* q_params = (const float*)d_in[2];
    const float* w_post   = (const float*)d_in[3];
    // d_in[4] = b_post: cancels inside batchnorm
    const float* gamma    = (const float*)d_in[5];
    const float* beta     = (const float*)d_in[6];
    float* out = (float*)d_out;

    unsigned short* weffb = (unsigned short*)d_ws;                    // 36,864 bf16
    float* psum   = (float*)((char*)d_ws + 36864 * 2);                // 64*4096 f32
    float* psq    = psum + (size_t)COUT * NBLK;
    float* scales = psq  + (size_t)COUT * NBLK;                       // 128 f32

    prep_weff<<<144, 256, 0, stream>>>(w_pre, q_params, w_post, weffb);
    conv_mfma<<<NBLK, 256, 0, stream>>>(x, weffb, out, psum, psq);
    reduce_scales<<<COUT, 256, 0, stream>>>(psum, psq, gamma, beta, scales);
    bn_relu<<<4096, 256, 0, stream>>>(out, scales);
}

// Round 3
// 881.326 us; speedup vs baseline: 1.4953x; 1.3777x over previous
//
#include <hip/hip_runtime.h>
#include <hip/hip_bf16.h>
#include <math.h>

typedef __attribute__((ext_vector_type(8))) short short8;
typedef __attribute__((ext_vector_type(4))) float floatx4;

#define EPSV 1e-5f

#define B_    16
#define CIN   64
#define H_IN  256
#define W_IN  256
#define COUT  64
#define H_OUT 254
#define W_OUT 254

#define NWT 4
#define NHT 64
#define NBLK (B_ * NWT * NHT)   // 4096

// fallback-path LDS ci stride
#define CIP 72

// ws layout (fast path): [weffb 128KB][psum 1MB][psq 1MB][scales..][pad][xn 128MB @4MB]
#define WEFF_OFF   0
#define PSUM_OFF   (128u << 10)
#define PSQ_OFF    (PSUM_OFF + (1u << 20))
#define SCALES_OFF (PSQ_OFF + (1u << 20))
#define XN_OFF     (4u << 20)
#define XN_BYTES   ((size_t)B_ * 256 * 256 * 64 * 2)   // 134,217,728

__device__ __forceinline__ unsigned short bf16u(float v) {
    __hip_bfloat16 b = __float2bfloat16(v);
    return *reinterpret_cast<unsigned short*>(&b);
}

// ---------------------------------------------------------------------------
// M = A*S1*A*S0 from q_params (L=2, Q=4, 3)
// ---------------------------------------------------------------------------
__device__ __forceinline__ void compute_M(const float* __restrict__ qp, float M[4][4]) {
    float s[2][4];
#pragma unroll
    for (int l = 0; l < 2; ++l)
#pragma unroll
        for (int q = 0; q < 4; ++q) {
            float tx = qp[l * 12 + q * 3 + 0];
            float ty = qp[l * 12 + q * 3 + 1];
            float tz = qp[l * 12 + q * 3 + 2];
            s[l][q] = cosf((tx + ty) * 0.5f) * cosf(tz);
        }
    float T[4][4];
#pragma unroll
    for (int i = 0; i < 4; ++i)
#pragma unroll
        for (int j = 0; j < 4; ++j) {
            float Aij = ((i >> 1) == (j >> 1)) ? 0.5f : 0.0f;
            T[i][j] = s[1][i] * Aij * s[0][j];
        }
#pragma unroll
    for (int i = 0; i < 4; ++i)
#pragma unroll
        for (int j = 0; j < 4; ++j) {
            int k0 = (i >> 1) * 2;
            M[i][j] = 0.5f * (T[k0][j] + T[k0 + 1][j]);
        }
}

// ---------------------------------------------------------------------------
// Kernel 1: fold w_pre/M/w_post -> bf16 weff[t][co][ci]   (t = kh*3+kw)
// ---------------------------------------------------------------------------
__global__ void prep_weff(const float* __restrict__ w_pre,
                          const float* __restrict__ q_params,
                          const float* __restrict__ w_post,
                          unsigned short* __restrict__ weffb) {
    int idx = blockIdx.x * 256 + threadIdx.x;
    if (idx >= 9 * 64 * 64) return;
    float M[4][4];
    compute_M(q_params, M);
    int ci = idx & 63;
    int co = (idx >> 6) & 63;
    int t  = idx >> 12;
    float v[4];
#pragma unroll
    for (int q = 0; q < 4; ++q) v[q] = w_pre[q * 576 + ci * 9 + t];
    float mv[4];
#pragma unroll
    for (int q = 0; q < 4; ++q)
        mv[q] = M[q][0] * v[0] + M[q][1] * v[1] + M[q][2] * v[2] + M[q][3] * v[3];
    float val = 0.f;
#pragma unroll
    for (int q = 0; q < 4; ++q) val += w_post[co * 4 + q] * mv[q];
    weffb[idx] = bf16u(val);
}

// ---------------------------------------------------------------------------
// Kernel T: x NCHW fp32 -> xn NHWC bf16  ([b][h][w][ci], ci innermost)
// block = 256 thr, tile = (b,h) x 128 w x 64 ci.  16 KB LDS, XOR-swizzled
// ci-chunks so both LDS write and read are conflict-free ds_*_b128.
// ---------------------------------------------------------------------------
__global__ __launch_bounds__(256) void transpose_x(const float* __restrict__ x,
                                                   unsigned short* __restrict__ xn) {
    __shared__ unsigned short T[128][64];   // [w][swizzled ci]
    const int bid = blockIdx.x;             // 16*256*2 = 8192
    const int wt  = bid & 1;
    const int h   = (bid >> 1) & 255;
    const int b   = bid >> 9;
    const int wb  = wt * 128;
    const int tid = threadIdx.x;
    const int wq  = tid & 31;   // w/4 within tile
    const int c8  = tid >> 5;   // ci chunk (8 ci each)

    // load 8 float4 (8 ci x 4 w), coalesced along w
    const float* xp = x + ((size_t)(b * 64 + c8 * 8) * 256 + h) * 256 + wb + wq * 4;
    floatx4 v[8];
#pragma unroll
    for (int i = 0; i < 8; ++i)
        v[i] = *reinterpret_cast<const floatx4*>(xp + (size_t)i * (256 * 256));

    // register-transpose -> 4 x (8 ci bf16) -> swizzled b128 LDS writes
#pragma unroll
    for (int j = 0; j < 4; ++j) {
        const int w = wq * 4 + j;
        unsigned short tmp[8];
#pragma unroll
        for (int i = 0; i < 8; ++i) tmp[i] = bf16u(v[i][j]);
        const int c8s = c8 ^ ((w >> 2) & 7);
        *reinterpret_cast<short8*>(&T[w][c8s * 8]) = *reinterpret_cast<short8*>(tmp);
    }
    __syncthreads();

    // coalesced 16B stores: task = (w, c8r), ci-chunk fastest
    unsigned short* outp = xn + ((size_t)(b * 256 + h) * 256 + wb) * 64;
#pragma unroll
    for (int p = 0; p < 4; ++p) {
        const int task = p * 256 + tid;
        const int c8r  = task & 7;
        const int w    = task >> 3;   // 0..127
        const int c8s  = c8r ^ ((w >> 2) & 7);
        short8 val = *reinterpret_cast<short8*>(&T[w][c8s * 8]);
        *reinterpret_cast<short8*>(outp + w * 64 + c8r * 8) = val;
    }
}

// ---------------------------------------------------------------------------
// Kernel 2 (fast): MFMA conv from NHWC bf16. No LDS, no barriers in main loop.
// Block: 64co x (4 rows x 64 cols); wave = one output row; dbuf A and B.
// ---------------------------------------------------------------------------
#define LOADA(dst, t_)                                                          \
    do {                                                                        \
        const unsigned short* wp_ = weffb + (t_) * 4096 + l15 * 64 + 8 * l4;    \
        _Pragma("unroll") for (int mi = 0; mi < 4; ++mi)                        \
        _Pragma("unroll") for (int ks = 0; ks < 2; ++ks)                        \
            dst[mi][ks] = *reinterpret_cast<const short8*>(wp_ + mi * 1024 + ks * 32); \
    } while (0)

#define LOADB(dst, kh_, kw_)                                                    \
    do {                                                                        \
        const unsigned short* xb_ = xr[kh_] + ((kw_) + l15) * 64 + 8 * l4;      \
        _Pragma("unroll") for (int nf = 0; nf < 4; ++nf)                        \
        _Pragma("unroll") for (int ks = 0; ks < 2; ++ks)                        \
            dst[nf][ks] = *reinterpret_cast<const short8*>(xb_ + nf * 1024 + ks * 32); \
    } while (0)

__global__ __launch_bounds__(256, 2) void conv_mfma_nhwc(
    const unsigned short* __restrict__ xn, const unsigned short* __restrict__ weffb,
    float* __restrict__ out, float* __restrict__ psum, float* __restrict__ psq)
{
    __shared__ float ssum[4][64];
    __shared__ float ssq[4][64];

    const int tid  = threadIdx.x;
    const int bid  = blockIdx.x;
    const int b    = bid >> 8;
    const int wt   = (bid >> 6) & 3;
    const int ht   = bid & 63;
    const int hb   = ht * 4;
    const int wb   = wt * 64;
    const int wave = tid >> 6;
    const int lane = tid & 63;
    const int l15  = lane & 15;
    const int l4   = lane >> 4;
    const int gh   = hb + wave;

    const unsigned short* xr[3];
    xr[0] = xn + ((size_t)((b * 256 + gh)) * 256 + wb) * 64;
    xr[1] = xr[0] + 256 * 64;
    xr[2] = xr[1] + 256 * 64;

    floatx4 acc[4][4];
#pragma unroll
    for (int mi = 0; mi < 4; ++mi)
#pragma unroll
        for (int nf = 0; nf < 4; ++nf) acc[mi][nf] = 0.f;

    short8 aA[4][2], aB[4][2], bA[4][2], bB[4][2];
    LOADA(aA, 0);
    LOADB(bA, 0, 0);

#pragma unroll
    for (int kh = 0; kh < 3; ++kh) {
#pragma unroll
        for (int kw = 0; kw < 3; ++kw) {
            const int t = kh * 3 + kw;
            if (t < 8) {
                const int t1  = t + 1;
                const int kh1 = t1 / 3;
                const int kw1 = t1 % 3;
                if (t & 1) { LOADA(aA, t1); LOADB(bA, kh1, kw1); }
                else       { LOADA(aB, t1); LOADB(bB, kh1, kw1); }
            }
#pragma unroll
            for (int mi = 0; mi < 4; ++mi)
#pragma unroll
                for (int nf = 0; nf < 4; ++nf)
#pragma unroll
                    for (int ks = 0; ks < 2; ++ks) {
                        const short8& a = (t & 1) ? aB[mi][ks] : aA[mi][ks];
                        const short8& bb = (t & 1) ? bB[nf][ks] : bA[nf][ks];
                        acc[mi][nf] = __builtin_amdgcn_mfma_f32_16x16x32_bf16(
                            a, bb, acc[mi][nf], 0, 0, 0);
                    }
        }
    }

    // ---- store conv output + BN partials
    const bool hvalid = gh < H_OUT;
    float ps[4][4], pq[4][4];
#pragma unroll
    for (int mi = 0; mi < 4; ++mi)
#pragma unroll
        for (int r = 0; r < 4; ++r) { ps[mi][r] = 0.f; pq[mi][r] = 0.f; }

#pragma unroll
    for (int mi = 0; mi < 4; ++mi)
#pragma unroll
        for (int nf = 0; nf < 4; ++nf) {
            const int  gw_o = wb + 16 * nf + l15;
            const bool vpix = hvalid && (gw_o < W_OUT);
#pragma unroll
            for (int r = 0; r < 4; ++r) {
                float val = acc[mi][nf][r];
                if (vpix) {
                    const int co = 16 * mi + 4 * l4 + r;
                    out[(((size_t)(b * 64 + co)) * H_OUT + gh) * W_OUT + gw_o] = val;
                    ps[mi][r] += val;
                    pq[mi][r] += val * val;
                }
            }
        }

#pragma unroll
    for (int mi = 0; mi < 4; ++mi)
#pragma unroll
        for (int r = 0; r < 4; ++r) {
            float s = ps[mi][r], q = pq[mi][r];
#pragma unroll
            for (int off = 1; off < 16; off <<= 1) {
                s += __shfl_xor(s, off);
                q += __shfl_xor(q, off);
            }
            if (l15 == 0) {
                ssum[wave][16 * mi + 4 * l4 + r] = s;
                ssq [wave][16 * mi + 4 * l4 + r] = q;
            }
        }
    __syncthreads();
    if (tid < 64) {
        float s = ssum[0][tid] + ssum[1][tid] + ssum[2][tid] + ssum[3][tid];
        float q = ssq [0][tid] + ssq [1][tid] + ssq [2][tid] + ssq [3][tid];
        psum[(size_t)tid * NBLK + bid] = s;
        psq [(size_t)tid * NBLK + bid] = q;
    }
}

// ---------------------------------------------------------------------------
// Kernel 2 (fallback, R2): MFMA conv with in-kernel NCHW staging
// ---------------------------------------------------------------------------
__global__ __launch_bounds__(256, 2) void conv_mfma_fb(
    const float* __restrict__ x, const unsigned short* __restrict__ weffb,
    float* __restrict__ out, float* __restrict__ psum, float* __restrict__ psq)
{
    __shared__ __align__(16) unsigned short xs[6 * 66 * CIP];
    __shared__ float ssum[4][64];
    __shared__ float ssq[4][64];

    const int tid  = threadIdx.x;
    const int bid  = blockIdx.x;
    const int b    = bid >> 8;
    const int wt   = (bid >> 6) & 3;
    const int ht   = bid & 63;
    const int hb   = ht * 4;
    const int wb   = wt * 64;
    const int wave = tid >> 6;
    const int lane = tid & 63;
    const int l15  = lane & 15;
    const int l4   = lane >> 4;

    for (int seg = wave; seg < 384; seg += 4) {
        int ci = seg / 6;
        int r  = seg - ci * 6;
        int gh = hb + r;
        const float* xrow = x + (((size_t)(b * 64 + ci)) * 256 + gh) * 256 + wb;
        float v = 0.f;
        if (gh < 256 && wb + lane < 256) v = xrow[lane];
        xs[(r * 66 + lane) * CIP + ci] = bf16u(v);
        if (lane < 2) {
            int c2 = 64 + lane;
            float v2 = 0.f;
            if (gh < 256 && wb + c2 < 256) v2 = xrow[c2];
            xs[(r * 66 + c2) * CIP + ci] = bf16u(v2);
        }
    }
    __syncthreads();

    floatx4 acc[4][4];
#pragma unroll
    for (int mi = 0; mi < 4; ++mi)
#pragma unroll
        for (int nf = 0; nf < 4; ++nf) acc[mi][nf] = 0.f;

    short8 afA[4][2], afB[4][2];
    LOADA(afA, 0);

#pragma unroll
    for (int kh = 0; kh < 3; ++kh) {
#pragma unroll
        for (int kw = 0; kw < 3; ++kw) {
            const int t = kh * 3 + kw;
            if (t < 8) {
                if (t & 1) { LOADA(afA, t + 1); }
                else       { LOADA(afB, t + 1); }
            }
            short8 bf[4][2];
            const unsigned short* xb = xs + ((wave + kh) * 66 + kw + l15) * CIP + 8 * l4;
#pragma unroll
            for (int nf = 0; nf < 4; ++nf)
#pragma unroll
                for (int ks = 0; ks < 2; ++ks)
                    bf[nf][ks] = *reinterpret_cast<const short8*>(xb + nf * 16 * CIP + ks * 32);
#pragma unroll
            for (int mi = 0; mi < 4; ++mi)
#pragma unroll
                for (int nf = 0; nf < 4; ++nf)
#pragma unroll
                    for (int ks = 0; ks < 2; ++ks) {
                        const short8& a = (t & 1) ? afB[mi][ks] : afA[mi][ks];
                        acc[mi][nf] = __builtin_amdgcn_mfma_f32_16x16x32_bf16(
                            a, bf[nf][ks], acc[mi][nf], 0, 0, 0);
                    }
        }
    }

    const int  gh_o   = hb + wave;
    const bool hvalid = gh_o < H_OUT;
    float ps[4][4], pq[4][4];
#pragma unroll
    for (int mi = 0; mi < 4; ++mi)
#pragma unroll
        for (int r = 0; r < 4; ++r) { ps[mi][r] = 0.f; pq[mi][r] = 0.f; }

#pragma unroll
    for (int mi = 0; mi < 4; ++mi)
#pragma unroll
        for (int nf = 0; nf < 4; ++nf) {
            const int  gw_o = wb + 16 * nf + l15;
            const bool vpix = hvalid && (gw_o < W_OUT);
#pragma unroll
            for (int r = 0; r < 4; ++r) {
                float val = acc[mi][nf][r];
                if (vpix) {
                    const int co = 16 * mi + 4 * l4 + r;
                    out[(((size_t)(b * 64 + co)) * H_OUT + gh_o) * W_OUT + gw_o] = val;
                    ps[mi][r] += val;
                    pq[mi][r] += val * val;
                }
            }
        }

#pragma unroll
    for (int mi = 0; mi < 4; ++mi)
#pragma unroll
        for (int r = 0; r < 4; ++r) {
            float s = ps[mi][r], q = pq[mi][r];
#pragma unroll
            for (int off = 1; off < 16; off <<= 1) {
                s += __shfl_xor(s, off);
                q += __shfl_xor(q, off);
            }
            if (l15 == 0) {
                ssum[wave][16 * mi + 4 * l4 + r] = s;
                ssq [wave][16 * mi + 4 * l4 + r] = q;
            }
        }
    __syncthreads();
    if (tid < 64) {
        float s = ssum[0][tid] + ssum[1][tid] + ssum[2][tid] + ssum[3][tid];
        float q = ssq [0][tid] + ssq [1][tid] + ssq [2][tid] + ssq [3][tid];
        psum[(size_t)tid * NBLK + bid] = s;
        psq [(size_t)tid * NBLK + bid] = q;
    }
}

// ---------------------------------------------------------------------------
// Kernel 3: reduce partials -> per-channel BN scale a, shift c
// ---------------------------------------------------------------------------
__global__ void reduce_scales(const float* __restrict__ psum,
                              const float* __restrict__ psq,
                              const float* __restrict__ gamma,
                              const float* __restrict__ beta,
                              float* __restrict__ scales) {
    const int co  = blockIdx.x;
    const int tid = threadIdx.x;
    float s = 0.f, q = 0.f;
    for (int i = tid; i < NBLK; i += 256) {
        s += psum[(size_t)co * NBLK + i];
        q += psq [(size_t)co * NBLK + i];
    }
    __shared__ float sh[4], sh2[4];
#pragma unroll
    for (int off = 32; off; off >>= 1) {
        s += __shfl_down(s, off);
        q += __shfl_down(q, off);
    }
    if ((tid & 63) == 0) { sh[tid >> 6] = s; sh2[tid >> 6] = q; }
    __syncthreads();
    if (tid == 0) {
        float S  = sh[0] + sh[1] + sh[2] + sh[3];
        float Q2 = sh2[0] + sh2[1] + sh2[2] + sh2[3];
        const float N = (float)(B_ * H_OUT * W_OUT);
        float mean = S / N;
        float var  = Q2 / N - mean * mean;
        float a = gamma[co] * rsqrtf(var + EPSV);
        float c = beta[co] - mean * a;
        scales[co]      = a;
        scales[64 + co] = c;
    }
}

// ---------------------------------------------------------------------------
// Kernel 4: in-place BN + ReLU over d_out (float4 vectorized)
// ---------------------------------------------------------------------------
__global__ __launch_bounds__(256) void bn_relu(float* __restrict__ out,
                                               const float* __restrict__ scales) {
    __shared__ float sa[64], sc[64];
    if (threadIdx.x < 64) sa[threadIdx.x] = scales[threadIdx.x];
    else if (threadIdx.x < 128) sc[threadIdx.x - 64] = scales[threadIdx.x];
    __syncthreads();
    const unsigned total4 = (unsigned)(B_ * COUT * H_OUT * W_OUT / 4);
    const unsigned plane4 = (unsigned)(H_OUT * W_OUT / 4);
    float4* p = (float4*)out;
    for (unsigned i = blockIdx.x * 256u + threadIdx.x; i < total4; i += gridDim.x * 256u) {
        unsigned co = (i / plane4) & 63u;
        float a = sa[co], c = sc[co];
        float4 v = p[i];
        v.x = fmaxf(fmaf(v.x, a, c), 0.f);
        v.y = fmaxf(fmaf(v.y, a, c), 0.f);
        v.z = fmaxf(fmaf(v.z, a, c), 0.f);
        v.w = fmaxf(fmaf(v.w, a, c), 0.f);
        p[i] = v;
    }
}

// ---------------------------------------------------------------------------
extern "C" void kernel_launch(void* const* d_in, const int* in_sizes, int n_in,
                              void* d_out, int out_size, void* d_ws, size_t ws_size,
                              hipStream_t stream) {
    const float* x        = (const float*)d_in[0];
    const float* w_pre    = (const float*)d_in[1];
    const float* q_params = (const float*)d_in[2];
    const float* w_post   = (const float*)d_in[3];
    const float* gamma    = (const float*)d_in[5];
    const float* beta     = (const float*)d_in[6];
    float* out = (float*)d_out;

    char* ws = (char*)d_ws;
    unsigned short* weffb = (unsigned short*)(ws + WEFF_OFF);
    float* psum   = (float*)(ws + PSUM_OFF);
    float* psq    = (float*)(ws + PSQ_OFF);
    float* scales = (float*)(ws + SCALES_OFF);
    unsigned short* xn = (unsigned short*)(ws + XN_OFF);

    const size_t need = (size_t)XN_OFF + XN_BYTES + (128u << 10);

    prep_weff<<<144, 256, 0, stream>>>(w_pre, q_params, w_post, weffb);
    if (ws_size >= need) {
        transpose_x<<<16 * 256 * 2, 256, 0, stream>>>(x, xn);
        conv_mfma_nhwc<<<NBLK, 256, 0, stream>>>(xn, weffb, out, psum, psq);
    } else {
        conv_mfma_fb<<<NBLK, 256, 0, stream>>>(x, weffb, out, psum, psq);
    }
    reduce_scales<<<COUT, 256, 0, stream>>>(psum, psq, gamma, beta, scales);
    bn_relu<<<4096, 256, 0, stream>>>(out, scales);
}